// Round 9
// baseline (68.850 us; speedup 1.0000x reference)
//
#include <hip/hip_runtime.h>
#include <math.h>

// Multi-scale RoIAlign (FPN), fp32 — bin-major register gather (R8 load path)
// + batched contiguous stores + barrier-free per-wave prologue.
// Block = (roi, 32 channels), 4 waves x 8 channels. Lane = output bin (49/64).
// Loads per channel: NARROW (bw<=4): 4 unaligned float4 tap-row loads with
// channel-invariant folded 4-weight dot. WIDE: 8 float2 loads. Accumulate 8
// channels in regs; epilogue transposes via per-wave LDS (8 ds_write_b32 +
// 2 ds_read_b128) into 98 aligned dwordx4 stores of 392 consecutive floats.
// No __syncthreads anywhere: each wave fills identical tables itself.

constexpr int CH = 256;
constexpr int POUT = 7;
constexpr int NSAMP = 14;           // POUT * SR
constexpr int NBIN = POUT * POUT;   // 49
constexpr int PER_ROI = CH * NBIN;  // 12544
constexpr int NWAVE = 4;
constexpr int CPW = 8;              // channels per wave
constexpr int CPB = NWAVE * CPW;    // 32 channels per block
constexpr int NCG = CH / CPB;       // 8 blocks per roi
constexpr int WOUT = CPW * NBIN;    // 392 floats per wave epilogue

struct F2 { float x, y; };
__device__ inline F2 ld2(const float* p) { F2 v; __builtin_memcpy(&v, p, 8); return v; }
struct F4 { float x, y, z, w; };
__device__ inline F4 ld4(const float* p) { F4 v; __builtin_memcpy(&v, p, 16); return v; }

__global__ __launch_bounds__(256)
void roi_align_bin2_kernel(const float* __restrict__ f0,
                           const float* __restrict__ f1,
                           const float* __restrict__ f2,
                           const float* __restrict__ f3,
                           const float* __restrict__ boxes,
                           float* __restrict__ out,
                           int K)
{
    __shared__ int   s_rowoff[2 * NSAMP];          // per-tap clamped row * W
    __shared__ float s_wy0[NSAMP], s_wy1[NSAMP];   // y weights (validity folded)
    __shared__ int   s_xlc[NSAMP];                 // x float2 col (<= W-2)
    __shared__ float s_ex0[NSAMP], s_ex1[NSAMP];   // x weights, edge+validity folded
    __shared__ alignas(16) float s_t[NWAVE][WOUT]; // per-wave store-transpose

    const int tid  = threadIdx.x;
    const int wave = tid >> 6;
    const int lane = tid & 63;
    const int roi  = blockIdx.x >> 3;              // NCG == 8
    const int cg   = blockIdx.x & (NCG - 1);
    const int b    = roi / K;

    const float bx1 = boxes[roi * 4 + 0], by1 = boxes[roi * 4 + 1];
    const float bx2 = boxes[roi * 4 + 2], by2 = boxes[roi * 4 + 3];

    const float area = (bx2 - bx1) * (by2 - by1);
    float lvlf = floorf(4.0f + log2f(sqrtf(area) / 224.0f + 1e-6f));
    lvlf = fminf(fmaxf(lvlf, 2.0f), 5.0f);
    const int lvl = (int)lvlf - 2;

    const float* feat; int H, W; float scale;
    if (lvl == 0)      { feat = f0; H = 200; W = 200; scale = 0.25f;    }
    else if (lvl == 1) { feat = f1; H = 100; W = 100; scale = 0.125f;   }
    else if (lvl == 2) { feat = f2; H = 50;  W = 50;  scale = 0.0625f;  }
    else               { feat = f3; H = 25;  W = 25;  scale = 0.03125f; }

    const float x1 = bx1 * scale, y1 = by1 * scale;
    const float rw = fmaxf(bx2 * scale - x1, 1.0f);
    const float rh = fmaxf(by2 * scale - y1, 1.0f);
    const float bw = rw * (1.0f / POUT);
    const float bh = rh * (1.0f / POUT);

    // Every wave fills the (identical) tables itself; same-value concurrent
    // writes from other waves are benign -> no __syncthreads needed.
    if (lane < 2 * NSAMP) {
        const bool isY = lane < NSAMP;
        const int i = isY ? lane : lane - NSAMP;
        const float dim   = isY ? (float)H : (float)W;
        const float start = isY ? y1 : x1;
        const float bsz   = isY ? bh : bw;
        const float p = start + ((float)i + 0.5f) * 0.5f * bsz;
        const float valid = (p >= -1.0f && p <= dim) ? 1.0f : 0.0f;
        const float pc = fminf(fmaxf(p, 0.0f), dim - 1.0f);
        const int q0 = (int)floorf(pc);
        const float l = pc - (float)q0;
        const float w0 = (1.0f - l) * valid;
        const float w1 = l * valid;
        if (isY) {
            const int q1 = min(q0 + 1, (int)dim - 1);
            s_rowoff[2 * i]     = q0 * W;
            s_rowoff[2 * i + 1] = q1 * W;
            s_wy0[i] = w0;
            s_wy1[i] = w1;
        } else {
            // float2 at col lc covers (lc, lc+1). If q0==W-1, fold w0 onto .y.
            const bool edge = (q0 > W - 2);
            s_xlc[i] = edge ? (W - 2) : q0;
            s_ex0[i] = edge ? 0.0f : w0;
            s_ex1[i] = edge ? (w1 + w0) : w1;
        }
    }
    asm volatile("s_waitcnt lgkmcnt(0)" ::: "memory");
    __builtin_amdgcn_sched_barrier(0);

    // Wave-uniform path decision: every bin's two x-samples fit a 4-col window.
    bool narrow = true;
    #pragma unroll
    for (int j = 0; j < POUT; ++j)
        narrow = narrow && (s_xlc[2 * j + 1] - s_xlc[2 * j] <= 2);

    // ---- per-lane (bin) channel-invariant state ----
    const int  lp = (lane < NBIN) ? lane : (NBIN - 1);
    const int  by = lp / POUT, bx = lp - POUT * by;

    const int ro0 = s_rowoff[4 * by + 0];
    const int ro1 = s_rowoff[4 * by + 1];
    const int ro2 = s_rowoff[4 * by + 2];
    const int ro3 = s_rowoff[4 * by + 3];
    const float wy0 = s_wy0[2 * by],     wy1 = s_wy1[2 * by];
    const float wy2 = s_wy0[2 * by + 1], wy3 = s_wy1[2 * by + 1];

    const int lc0 = s_xlc[2 * bx], lc1 = s_xlc[2 * bx + 1];
    const float e00 = s_ex0[2 * bx],     e01 = s_ex1[2 * bx];
    const float e10 = s_ex0[2 * bx + 1], e11 = s_ex1[2 * bx + 1];

    const int HW = H * W;
    const int cbase = cg * CPB + wave * CPW;
    const float* chan0 = feat + ((size_t)b * CH + cbase) * (size_t)HW;

    float a[CPW];

    if (narrow) {
        const int base = min(lc0, W - 4);
        const int i0 = lc0 - base;          // 0..2 (>0 only at right edge)
        const int i1 = lc1 - base;          // i0..2
        const float w40 = (i0 == 0 ? e00 : 0.0f) + (i1 == 0 ? e10 : 0.0f);
        const float w41 = (i0 == 1 ? e00 : 0.0f) + (i0 == 0 ? e01 : 0.0f)
                        + (i1 == 1 ? e10 : 0.0f) + (i1 == 0 ? e11 : 0.0f);
        const float w42 = (i0 == 2 ? e00 : 0.0f) + (i0 == 1 ? e01 : 0.0f)
                        + (i1 == 2 ? e10 : 0.0f) + (i1 == 1 ? e11 : 0.0f);
        const float w43 = (i0 == 2 ? e01 : 0.0f) + (i1 == 2 ? e11 : 0.0f);

        F4 v0 = ld4(chan0 + ro0 + base);
        F4 v1 = ld4(chan0 + ro1 + base);
        F4 v2 = ld4(chan0 + ro2 + base);
        F4 v3 = ld4(chan0 + ro3 + base);

        #pragma unroll
        for (int c = 0; c < CPW; ++c) {
            F4 n0, n1, n2, n3;
            if (c + 1 < CPW) {
                const float* ch = chan0 + (size_t)(c + 1) * HW;
                n0 = ld4(ch + ro0 + base);
                n1 = ld4(ch + ro1 + base);
                n2 = ld4(ch + ro2 + base);
                n3 = ld4(ch + ro3 + base);
            }
            const float rv0 = v0.x * w40 + v0.y * w41 + v0.z * w42 + v0.w * w43;
            const float rv1 = v1.x * w40 + v1.y * w41 + v1.z * w42 + v1.w * w43;
            const float rv2 = v2.x * w40 + v2.y * w41 + v2.z * w42 + v2.w * w43;
            const float rv3 = v3.x * w40 + v3.y * w41 + v3.z * w42 + v3.w * w43;
            a[c] = (wy0 * rv0 + wy1 * rv1 + wy2 * rv2 + wy3 * rv3) * 0.25f;
            v0 = n0; v1 = n1; v2 = n2; v3 = n3;
        }
    } else {
        F2 a0 = ld2(chan0 + ro0 + lc0), d0 = ld2(chan0 + ro0 + lc1);
        F2 a1 = ld2(chan0 + ro1 + lc0), d1 = ld2(chan0 + ro1 + lc1);
        F2 a2 = ld2(chan0 + ro2 + lc0), d2 = ld2(chan0 + ro2 + lc1);
        F2 a3 = ld2(chan0 + ro3 + lc0), d3 = ld2(chan0 + ro3 + lc1);

        #pragma unroll
        for (int c = 0; c < CPW; ++c) {
            F2 na0, na1, na2, na3, nd0, nd1, nd2, nd3;
            if (c + 1 < CPW) {
                const float* ch = chan0 + (size_t)(c + 1) * HW;
                na0 = ld2(ch + ro0 + lc0); nd0 = ld2(ch + ro0 + lc1);
                na1 = ld2(ch + ro1 + lc0); nd1 = ld2(ch + ro1 + lc1);
                na2 = ld2(ch + ro2 + lc0); nd2 = ld2(ch + ro2 + lc1);
                na3 = ld2(ch + ro3 + lc0); nd3 = ld2(ch + ro3 + lc1);
            }
            const float rv0 = e00 * a0.x + e01 * a0.y + e10 * d0.x + e11 * d0.y;
            const float rv1 = e00 * a1.x + e01 * a1.y + e10 * d1.x + e11 * d1.y;
            const float rv2 = e00 * a2.x + e01 * a2.y + e10 * d2.x + e11 * d2.y;
            const float rv3 = e00 * a3.x + e01 * a3.y + e10 * d3.x + e11 * d3.y;
            a[c] = (wy0 * rv0 + wy1 * rv1 + wy2 * rv2 + wy3 * rv3) * 0.25f;
            a0 = na0; a1 = na1; a2 = na2; a3 = na3;
            d0 = nd0; d1 = nd1; d2 = nd2; d3 = nd3;
        }
    }

    // ---- epilogue: per-wave LDS transpose -> contiguous dwordx4 stores ----
    float* wt = s_t[wave];
    if (lane < NBIN) {
        #pragma unroll
        for (int c = 0; c < CPW; ++c)
            wt[c * NBIN + lane] = a[c];
    }
    asm volatile("s_waitcnt lgkmcnt(0)" ::: "memory");
    __builtin_amdgcn_sched_barrier(0);

    float* wout = out + (size_t)roi * PER_ROI + (size_t)cbase * NBIN;
    {
        const float4 v = *(const float4*)(wt + 4 * lane);          // slots 0..63
        *(float4*)(wout + 4 * lane) = v;
    }
    if (lane < WOUT / 4 - 64) {                                    // slots 64..97
        const int s = 64 + lane;
        const float4 v = *(const float4*)(wt + 4 * s);
        *(float4*)(wout + 4 * s) = v;
    }
}

extern "C" void kernel_launch(void* const* d_in, const int* in_sizes, int n_in,
                              void* d_out, int out_size, void* d_ws, size_t ws_size,
                              hipStream_t stream) {
    const float* f0    = (const float*)d_in[0];
    const float* f1    = (const float*)d_in[1];
    const float* f2    = (const float*)d_in[2];
    const float* f3    = (const float*)d_in[3];
    const float* boxes = (const float*)d_in[4];
    float* out = (float*)d_out;

    const int B    = in_sizes[0] / (256 * 200 * 200);
    const int nroi = in_sizes[4] / 4;
    const int K    = nroi / B;

    roi_align_bin2_kernel<<<nroi * NCG, 256, 0, stream>>>(f0, f1, f2, f3, boxes, out, K);
}

// Round 10
// 64.926 us; speedup vs baseline: 1.0604x; 1.0604x over previous
//
#include <hip/hip_runtime.h>
#include <math.h>

// Multi-scale RoIAlign (FPN), fp32 — bin-major register-only gather (R8 load
// path), CPW=16 to amortize the per-block prologue (box load + table build).
// Block = (roi, 32 channels), 2 waves x 16 channels. Lane = output bin (49/64).
// NARROW rois (bw<=4, ~all of level>=1 + most level-0): 4 unaligned float4
// tap-row loads/channel + channel-invariant folded 4-weight dot -> 5 VMEM
// instrs, zero LDS in the loop. WIDE: 8 float2 loads. Register double-buffer
// across the 16-channel loop. 0.25 mean factor folded into wy tables.

constexpr int CH = 256;
constexpr int POUT = 7;
constexpr int NSAMP = 14;           // POUT * SR
constexpr int NBIN = POUT * POUT;   // 49
constexpr int PER_ROI = CH * NBIN;  // 12544
constexpr int NWAVE = 2;
constexpr int CPW = 16;             // channels per wave
constexpr int CPB = NWAVE * CPW;    // 32 channels per block
constexpr int NCG = CH / CPB;       // 8 blocks per roi

struct F2 { float x, y; };
__device__ inline F2 ld2(const float* p) { F2 v; __builtin_memcpy(&v, p, 8); return v; }
struct F4 { float x, y, z, w; };
__device__ inline F4 ld4(const float* p) { F4 v; __builtin_memcpy(&v, p, 16); return v; }

__global__ __launch_bounds__(128)
void roi_align_bin3_kernel(const float* __restrict__ f0,
                           const float* __restrict__ f1,
                           const float* __restrict__ f2,
                           const float* __restrict__ f3,
                           const float* __restrict__ boxes,
                           float* __restrict__ out,
                           int K)
{
    __shared__ int   s_rowoff[2 * NSAMP];          // per-tap clamped row * W
    __shared__ float s_wy0[NSAMP], s_wy1[NSAMP];   // y weights * 0.25 (validity folded)
    __shared__ int   s_xlc[NSAMP];                 // x float2 col (<= W-2)
    __shared__ float s_ex0[NSAMP], s_ex1[NSAMP];   // x weights, edge+validity folded

    const int tid  = threadIdx.x;
    const int wave = tid >> 6;
    const int lane = tid & 63;
    const int roi  = blockIdx.x >> 3;              // NCG == 8
    const int cg   = blockIdx.x & (NCG - 1);
    const int b    = roi / K;

    const float bx1 = boxes[roi * 4 + 0], by1 = boxes[roi * 4 + 1];
    const float bx2 = boxes[roi * 4 + 2], by2 = boxes[roi * 4 + 3];

    const float area = (bx2 - bx1) * (by2 - by1);
    float lvlf = floorf(4.0f + log2f(sqrtf(area) / 224.0f + 1e-6f));
    lvlf = fminf(fmaxf(lvlf, 2.0f), 5.0f);
    const int lvl = (int)lvlf - 2;

    const float* feat; int H, W; float scale;
    if (lvl == 0)      { feat = f0; H = 200; W = 200; scale = 0.25f;    }
    else if (lvl == 1) { feat = f1; H = 100; W = 100; scale = 0.125f;   }
    else if (lvl == 2) { feat = f2; H = 50;  W = 50;  scale = 0.0625f;  }
    else               { feat = f3; H = 25;  W = 25;  scale = 0.03125f; }

    const float x1 = bx1 * scale, y1 = by1 * scale;
    const float rw = fmaxf(bx2 * scale - x1, 1.0f);
    const float rh = fmaxf(by2 * scale - y1, 1.0f);
    const float bw = rw * (1.0f / POUT);
    const float bh = rh * (1.0f / POUT);

    if (tid < 2 * NSAMP) {
        const bool isY = tid < NSAMP;
        const int i = isY ? tid : tid - NSAMP;
        const float dim   = isY ? (float)H : (float)W;
        const float start = isY ? y1 : x1;
        const float bsz   = isY ? bh : bw;
        const float p = start + ((float)i + 0.5f) * 0.5f * bsz;
        const float valid = (p >= -1.0f && p <= dim) ? 1.0f : 0.0f;
        const float pc = fminf(fmaxf(p, 0.0f), dim - 1.0f);
        const int q0 = (int)floorf(pc);
        const float l = pc - (float)q0;
        const float w0 = (1.0f - l) * valid;
        const float w1 = l * valid;
        if (isY) {
            const int q1 = min(q0 + 1, (int)dim - 1);
            s_rowoff[2 * i]     = q0 * W;
            s_rowoff[2 * i + 1] = q1 * W;
            s_wy0[i] = w0 * 0.25f;                 // fold sample mean
            s_wy1[i] = w1 * 0.25f;
        } else {
            // float2 at col lc covers (lc, lc+1). If q0==W-1, fold w0 onto .y.
            const bool edge = (q0 > W - 2);
            s_xlc[i] = edge ? (W - 2) : q0;
            s_ex0[i] = edge ? 0.0f : w0;
            s_ex1[i] = edge ? (w1 + w0) : w1;
        }
    }
    __syncthreads();

    // Wave-uniform path decision: every bin's two x-samples fit a 4-col window.
    bool narrow = true;
    #pragma unroll
    for (int j = 0; j < POUT; ++j)
        narrow = narrow && (s_xlc[2 * j + 1] - s_xlc[2 * j] <= 2);

    // ---- per-lane (bin) channel-invariant state ----
    const int  lp = (lane < NBIN) ? lane : (NBIN - 1);
    const bool act = (lane < NBIN);
    const int  by = lp / POUT, bx = lp - POUT * by;

    const int ro0 = s_rowoff[4 * by + 0];
    const int ro1 = s_rowoff[4 * by + 1];
    const int ro2 = s_rowoff[4 * by + 2];
    const int ro3 = s_rowoff[4 * by + 3];
    const float wy0 = s_wy0[2 * by],     wy1 = s_wy1[2 * by];
    const float wy2 = s_wy0[2 * by + 1], wy3 = s_wy1[2 * by + 1];

    const int lc0 = s_xlc[2 * bx], lc1 = s_xlc[2 * bx + 1];
    const float e00 = s_ex0[2 * bx],     e01 = s_ex1[2 * bx];
    const float e10 = s_ex0[2 * bx + 1], e11 = s_ex1[2 * bx + 1];

    const int HW = H * W;
    const int cbase = cg * CPB + wave * CPW;
    const float* chan0 = feat + ((size_t)b * CH + cbase) * (size_t)HW;
    const size_t obase = (size_t)roi * PER_ROI + (size_t)cbase * NBIN + lp;

    if (narrow) {
        const int base = min(lc0, W - 4);
        const int i0 = lc0 - base;          // 0..2 (>0 only at right edge)
        const int i1 = lc1 - base;          // i0..2
        const float w40 = (i0 == 0 ? e00 : 0.0f) + (i1 == 0 ? e10 : 0.0f);
        const float w41 = (i0 == 1 ? e00 : 0.0f) + (i0 == 0 ? e01 : 0.0f)
                        + (i1 == 1 ? e10 : 0.0f) + (i1 == 0 ? e11 : 0.0f);
        const float w42 = (i0 == 2 ? e00 : 0.0f) + (i0 == 1 ? e01 : 0.0f)
                        + (i1 == 2 ? e10 : 0.0f) + (i1 == 1 ? e11 : 0.0f);
        const float w43 = (i0 == 2 ? e01 : 0.0f) + (i1 == 2 ? e11 : 0.0f);

        F4 v0 = ld4(chan0 + ro0 + base);
        F4 v1 = ld4(chan0 + ro1 + base);
        F4 v2 = ld4(chan0 + ro2 + base);
        F4 v3 = ld4(chan0 + ro3 + base);

        #pragma unroll
        for (int c = 0; c < CPW; ++c) {
            F4 n0, n1, n2, n3;
            if (c + 1 < CPW) {
                const float* ch = chan0 + (size_t)(c + 1) * HW;
                n0 = ld4(ch + ro0 + base);
                n1 = ld4(ch + ro1 + base);
                n2 = ld4(ch + ro2 + base);
                n3 = ld4(ch + ro3 + base);
            }
            const float rv0 = v0.x * w40 + v0.y * w41 + v0.z * w42 + v0.w * w43;
            const float rv1 = v1.x * w40 + v1.y * w41 + v1.z * w42 + v1.w * w43;
            const float rv2 = v2.x * w40 + v2.y * w41 + v2.z * w42 + v2.w * w43;
            const float rv3 = v3.x * w40 + v3.y * w41 + v3.z * w42 + v3.w * w43;
            const float acc = wy0 * rv0 + wy1 * rv1 + wy2 * rv2 + wy3 * rv3;
            if (act) out[obase + (size_t)c * NBIN] = acc;
            v0 = n0; v1 = n1; v2 = n2; v3 = n3;
        }
    } else {
        F2 a0 = ld2(chan0 + ro0 + lc0), d0 = ld2(chan0 + ro0 + lc1);
        F2 a1 = ld2(chan0 + ro1 + lc0), d1 = ld2(chan0 + ro1 + lc1);
        F2 a2 = ld2(chan0 + ro2 + lc0), d2 = ld2(chan0 + ro2 + lc1);
        F2 a3 = ld2(chan0 + ro3 + lc0), d3 = ld2(chan0 + ro3 + lc1);

        #pragma unroll
        for (int c = 0; c < CPW; ++c) {
            F2 na0, na1, na2, na3, nd0, nd1, nd2, nd3;
            if (c + 1 < CPW) {
                const float* ch = chan0 + (size_t)(c + 1) * HW;
                na0 = ld2(ch + ro0 + lc0); nd0 = ld2(ch + ro0 + lc1);
                na1 = ld2(ch + ro1 + lc0); nd1 = ld2(ch + ro1 + lc1);
                na2 = ld2(ch + ro2 + lc0); nd2 = ld2(ch + ro2 + lc1);
                na3 = ld2(ch + ro3 + lc0); nd3 = ld2(ch + ro3 + lc1);
            }
            const float rv0 = e00 * a0.x + e01 * a0.y + e10 * d0.x + e11 * d0.y;
            const float rv1 = e00 * a1.x + e01 * a1.y + e10 * d1.x + e11 * d1.y;
            const float rv2 = e00 * a2.x + e01 * a2.y + e10 * d2.x + e11 * d2.y;
            const float rv3 = e00 * a3.x + e01 * a3.y + e10 * d3.x + e11 * d3.y;
            const float acc = wy0 * rv0 + wy1 * rv1 + wy2 * rv2 + wy3 * rv3;
            if (act) out[obase + (size_t)c * NBIN] = acc;
            a0 = na0; a1 = na1; a2 = na2; a3 = na3;
            d0 = nd0; d1 = nd1; d2 = nd2; d3 = nd3;
        }
    }
}

extern "C" void kernel_launch(void* const* d_in, const int* in_sizes, int n_in,
                              void* d_out, int out_size, void* d_ws, size_t ws_size,
                              hipStream_t stream) {
    const float* f0    = (const float*)d_in[0];
    const float* f1    = (const float*)d_in[1];
    const float* f2    = (const float*)d_in[2];
    const float* f3    = (const float*)d_in[3];
    const float* boxes = (const float*)d_in[4];
    float* out = (float*)d_out;

    const int B    = in_sizes[0] / (256 * 200 * 200);
    const int nroi = in_sizes[4] / 4;
    const int K    = nroi / B;

    roi_align_bin3_kernel<<<nroi * NCG, 128, 0, stream>>>(f0, f1, f2, f3, boxes, out, K);
}